// Round 11
// baseline (644.268 us; speedup 1.0000x reference)
//
#include <hip/hip_runtime.h>
#include <hip/hip_cooperative_groups.h>

namespace cg = cooperative_groups;

// EdgeGate: out[e] = silu(f(e) @ W1 + b1) @ W2 + b2,
//   f(e) = [|H_u - H_v| (128), H_u*H_v (128), S_e, F_e]   (258)
//
// R11: R10's m-blocking spilled (WRITE 23->67MB) -> reverted to R7 core.
// Two orthogonal cuts:
//  (1) K-permutation changed so even chunks = |diff| of 8 consecutive dims,
//      odd chunks = prod of same dims: A-frags are ae=|u8-v8|, ao=u8*v8
//      directly -- the ~64 interleave VALU ops/tile/lane are gone.
//  (2) ONE cooperative mega-kernel (zero+cvt | hist | scan | scatter | main
//      with grid.sync between phases) removes ~6 launch overheads (~15us
//      each). Falls back to the proven 6-dispatch path if cooperative
//      launch is refused.
// Locality machinery unchanged (canon swap, (a/6250,b>>3) sort, XCC_ID-
// pinned ordered ticket queues + steal; FETCH 53MB proven in R7).

typedef _Float16       half8   __attribute__((ext_vector_type(8)));
typedef _Float16       half4v  __attribute__((ext_vector_type(4)));
typedef unsigned short ushort8 __attribute__((ext_vector_type(8)));
typedef float          f32x4   __attribute__((ext_vector_type(4)));

#define NSEG    8

__device__ __forceinline__ float silu_f(float x) {
    return x / (1.0f + __expf(-x));
}

__device__ __forceinline__ void canon(int u, int v, int& a, int& b) {
    const int sw = (u ^ v) & 1;       // balanced, symmetric in (u,v)
    a = sw ? v : u;
    b = sw ? u : v;
}

// ---------------- W1 LDS staging ----------------
// w1t[n][kp] f16. kp = c*32 + k32 (c = chunk, k32 = q*8+j).
// src row = (c&1)*128 + (c>>1)*32 + k32  (even c -> diff row, odd -> prod).
// Stored as 16B blocks kb (= kp>>3) at kb ^ (n&7) (XOR swizzle).

__device__ __forceinline__ void stage_w1(const float* __restrict__ W1,
                                         _Float16* __restrict__ w1t, int tid) {
    const int n = tid & 127;
    const int g = tid >> 7;
    #pragma unroll
    for (int i = 0; i < 8; ++i) {
        const int kb = g + (i << 2);
        half8 tmp;
        #pragma unroll
        for (int j = 0; j < 8; ++j) {
            const int kp  = (kb << 3) + j;
            const int c   = kp >> 5;
            const int k32 = kp & 31;
            const int src = ((c & 1) << 7) + ((c >> 1) << 5) + k32;
            tmp[j] = (_Float16)W1[src * 128 + n];
        }
        *(half8*)&w1t[n * 256 + ((kb ^ (n & 7)) << 3)] = tmp;
    }
}

// ---------------- shared main compute (one 16-edge group per wave) ----------------

__device__ __forceinline__ void edge_tile16(
    const _Float16* __restrict__ Hh, const int4* __restrict__ recs,
    const _Float16* __restrict__ w1t,
    const float* __restrict__ W1, const float* __restrict__ b1,
    const float* __restrict__ W2, float b2v, float* __restrict__ out,
    int ebase, int elim, int q, int cb, int swz)
{
    const int e = min(ebase + cb, elim - 1);     // clamp; stores guarded
    const int4 r = recs[e];
    const int a = r.x, b = r.y, oe = r.z;
    const unsigned pk = (unsigned)r.w;
    const unsigned short sl = (unsigned short)(pk & 0xFFFF);
    const unsigned short fl = (unsigned short)(pk >> 16);
    const float Sf = (float)*(const _Float16*)&sl;
    const float Ff = (float)*(const _Float16*)&fl;

    const _Float16* up = Hh + (size_t)a * 128;
    const _Float16* vp = Hh + (size_t)b * 128;

    f32x4 acc[8];
    #pragma unroll
    for (int t = 0; t < 8; ++t) acc[t] = (f32x4){0.f, 0.f, 0.f, 0.f};

    #pragma unroll
    for (int c8 = 0; c8 < 4; ++c8) {
        const half8 u8 = *(const half8*)(up + (c8 << 5) + (q << 3));
        const half8 v8 = *(const half8*)(vp + (c8 << 5) + (q << 3));
        half8 d8 = u8 - v8;
        ushort8 du = *(ushort8*)&d8;
        du = du & (unsigned short)0x7FFF;          // |diff|
        const half8 ae = *(half8*)&du;             // even chunk A-frag
        const half8 ao = u8 * v8;                  // odd  chunk A-frag

        const int kb0 = ((c8 << 3) + q) ^ swz;
        const int kb1 = ((c8 << 3) + 4 + q) ^ swz;
        #pragma unroll
        for (int t = 0; t < 8; ++t) {
            const half8 b0 = *(const half8*)&w1t[((t << 4) + cb) * 256 + (kb0 << 3)];
            acc[t] = __builtin_amdgcn_mfma_f32_16x16x32_f16(ae, b0, acc[t], 0, 0, 0);
        }
        #pragma unroll
        for (int t = 0; t < 8; ++t) {
            const half8 b1f = *(const half8*)&w1t[((t << 4) + cb) * 256 + (kb1 << 3)];
            acc[t] = __builtin_amdgcn_mfma_f32_16x16x32_f16(ao, b1f, acc[t], 0, 0, 0);
        }
    }

    // epilogue: per-quad row data via shuffle from lanes cb = q*4+r
    float s_r[4], f_r[4]; int oe_r[4];
    #pragma unroll
    for (int rr = 0; rr < 4; ++rr) {
        const int src = (q << 2) + rr;
        s_r[rr]  = __shfl(Sf, src);
        f_r[rr]  = __shfl(Ff, src);
        oe_r[rr] = __shfl(oe, src);
    }

    float rs[4] = {0.f, 0.f, 0.f, 0.f};
    #pragma unroll
    for (int t = 0; t < 8; ++t) {
        const int col    = (t << 4) + cb;
        const float w256 = W1[32768 + col];
        const float w257 = W1[32896 + col];
        const float b1c  = b1[col];
        const float w2c  = W2[col];
        const f32x4 av = acc[t];
        #pragma unroll
        for (int rr = 0; rr < 4; ++rr)
            rs[rr] += silu_f(av[rr] + s_r[rr] * w256 + f_r[rr] * w257 + b1c) * w2c;
    }

    #pragma unroll
    for (int off = 1; off < 16; off <<= 1) {
        #pragma unroll
        for (int rr = 0; rr < 4; ++rr) rs[rr] += __shfl_xor(rs[rr], off);
    }

    if (cb == 0) {
        #pragma unroll
        for (int rr = 0; rr < 4; ++rr) {
            const int pe = ebase + (q << 2) + rr;
            if (pe < elim) out[oe_r[rr]] = rs[rr] + b2v;
        }
    }
}

// ---------------- cooperative mega-kernel ----------------

__global__ __launch_bounds__(512, 4)
void edgegate_mega(const float* __restrict__ H, _Float16* __restrict__ Hh,
                   const int* __restrict__ eidx,
                   const float* __restrict__ Se, const float* __restrict__ Fe,
                   const float* __restrict__ W1, const float* __restrict__ b1,
                   const float* __restrict__ W2, const float* __restrict__ b2,
                   float* __restrict__ out,
                   int* __restrict__ hist,   // [NB+8]; ctr = hist+NB
                   int* __restrict__ bsum,   // [512]
                   int* __restrict__ vbs,    // [9]
                   int4* __restrict__ recs,  // [E]
                   int E, int n4, int NB, int ASZ, int BBINS)
{
    cg::grid_group grid = cg::this_grid();
    __shared__ _Float16 w1t[128 * 256];   // 64 KiB
    __shared__ int s[512];                // scan scratch
    __shared__ int tkt[2];                // ticket parity slots

    const int tid = threadIdx.x;
    const int gid = blockIdx.x * blockDim.x + tid;
    const int G   = gridDim.x * blockDim.x;

    // ---- phase 0: zero hist+ctr, convert H -> f16, stage W1 to LDS
    for (int i = gid; i < NB + 8; i += G) hist[i] = 0;
    for (int i = gid; i < n4; i += G) {
        const float4 f = ((const float4*)H)[i];
        half4v h;
        h[0] = (_Float16)f.x; h[1] = (_Float16)f.y;
        h[2] = (_Float16)f.z; h[3] = (_Float16)f.w;
        ((half4v*)Hh)[i] = h;
    }
    stage_w1(W1, w1t, tid);
    grid.sync();

    // ---- phase 1: histogram
    for (int e = gid; e < E; e += G) {
        int a, b;
        canon(eidx[e], eidx[E + e], a, b);
        atomicAdd(&hist[(a / ASZ) * BBINS + (b >> 3)], 1);
    }
    grid.sync();

    // ---- phase 2: exclusive scan of hist (block chunk + bsum + add-back)
    const int CH    = (NB + (int)gridDim.x - 1) / (int)gridDim.x;  // 98
    const int myBin = blockIdx.x * CH + tid;
    const int bval  = (tid < CH && myBin < NB) ? hist[myBin] : 0;
    s[tid] = bval;
    __syncthreads();
    for (int off = 1; off < 512; off <<= 1) {
        const int x = (tid >= off) ? s[tid - off] : 0;
        __syncthreads();
        s[tid] += x;
        __syncthreads();
    }
    const int incl = s[tid];
    if (tid == 511) bsum[blockIdx.x] = incl;
    grid.sync();

    if (blockIdx.x == 0) {
        const int bv = bsum[tid];
        s[tid] = bv;
        __syncthreads();
        for (int off = 1; off < 512; off <<= 1) {
            const int x = (tid >= off) ? s[tid - off] : 0;
            __syncthreads();
            s[tid] += x;
            __syncthreads();
        }
        bsum[tid] = s[tid] - bv;   // exclusive
    }
    grid.sync();

    if (tid < CH && myBin < NB) {
        const int gv = (incl - bval) + bsum[blockIdx.x];
        hist[myBin] = gv;
        if (myBin % BBINS == 0) vbs[myBin / BBINS] = gv;
    }
    if (gid == 0) vbs[NSEG] = E;
    grid.sync();

    // ---- phase 3: scatter into sorted records
    for (int e = gid; e < E; e += G) {
        int a, b;
        canon(eidx[e], eidx[E + e], a, b);
        const int key = (a / ASZ) * BBINS + (b >> 3);
        const int pos = atomicAdd(&hist[key], 1);
        _Float16 sh = (_Float16)Se[e];
        _Float16 fh = (_Float16)Fe[e];
        unsigned pk = (unsigned)*(unsigned short*)&sh
                    | ((unsigned)*(unsigned short*)&fh << 16);
        recs[pos] = make_int4(a, b, e, (int)pk);
    }
    grid.sync();

    // ---- phase 4: main compute (XCD-pinned ordered ticket queues + steal)
    int xcd;
    asm volatile("s_getreg_b32 %0, hwreg(HW_REG_XCC_ID)" : "=s"(xcd));
    xcd &= (NSEG - 1);

    int* ctr = hist + NB;
    const int lane = tid & 63;
    const int wave = tid >> 6;
    const int q    = lane >> 4;
    const int cb   = lane & 15;
    const int swz  = cb & 7;
    const float b2v = b2[0];

    int p = 0;
    for (int sidx = 0; sidx < NSEG; ++sidx) {
        const int seg = (xcd + sidx) & (NSEG - 1);
        const int vs  = vbs[seg];
        const int ve  = vbs[seg + 1];
        const int ner = ve - vs;
        if (ner <= 0) continue;
        const int Tt = (ner + 127) >> 7;    // 128-edge tickets

        while (true) {
            if (tid == 0) tkt[p] = atomicAdd(&ctr[seg], 1);
            __syncthreads();
            const int t0 = tkt[p];
            p ^= 1;
            if (t0 >= Tt) break;
            const int ebase = vs + (t0 << 7) + (wave << 4);
            edge_tile16(Hh, recs, w1t, W1, b1, W2, b2v, out, ebase, ve, q, cb, swz);
        }
    }
}

// ---------------- fallback pre-passes (proven in R10) ----------------

__global__ __launch_bounds__(256)
void cvt_zero_kernel(const float* __restrict__ H, _Float16* __restrict__ Hh,
                     int n4, int* __restrict__ zp, int nz) {
    int i = blockIdx.x * blockDim.x + threadIdx.x;
    if (i < nz) zp[i] = 0;
    if (i < n4) {
        const float4 f = ((const float4*)H)[i];
        half4v h;
        h[0] = (_Float16)f.x; h[1] = (_Float16)f.y;
        h[2] = (_Float16)f.z; h[3] = (_Float16)f.w;
        ((half4v*)Hh)[i] = h;
    }
}

__global__ __launch_bounds__(256)
void hist_kernel(const int* __restrict__ eidx, int* __restrict__ hist,
                 int E, int ASZ, int BBINS) {
    int e = blockIdx.x * blockDim.x + threadIdx.x;
    if (e < E) {
        int a, b;
        canon(eidx[e], eidx[E + e], a, b);
        atomicAdd(&hist[(a / ASZ) * BBINS + (b >> 3)], 1);
    }
}

__global__ __launch_bounds__(256)
void scan1_kernel(int* __restrict__ hist, int* __restrict__ bsum, int NB) {
    __shared__ int s[256];
    const int t = threadIdx.x;
    const int i = blockIdx.x * 256 + t;
    const int v = (i < NB) ? hist[i] : 0;
    s[t] = v;
    __syncthreads();
    for (int off = 1; off < 256; off <<= 1) {
        const int x = (t >= off) ? s[t - off] : 0;
        __syncthreads();
        s[t] += x;
        __syncthreads();
    }
    if (i < NB) hist[i] = s[t] - v;
    if (t == 255) bsum[blockIdx.x] = s[255];
}

__global__ __launch_bounds__(256)
void scan2_kernel(int* __restrict__ bsum, int nb1,
                  const int* __restrict__ hist, int* __restrict__ vbs,
                  int BBINS, int E) {
    __shared__ int s[256];
    const int t = threadIdx.x;
    const int v = (t < nb1) ? bsum[t] : 0;
    s[t] = v;
    __syncthreads();
    for (int off = 1; off < 256; off <<= 1) {
        const int x = (t >= off) ? s[t - off] : 0;
        __syncthreads();
        s[t] += x;
        __syncthreads();
    }
    if (t < nb1) bsum[t] = s[t] - v;   // exclusive
    __syncthreads();
    if (t < NSEG) {
        const int idx = t * BBINS;
        vbs[t] = hist[idx] + bsum[idx >> 8];
    } else if (t == NSEG) {
        vbs[NSEG] = E;
    }
}

__global__ __launch_bounds__(256)
void scatter_kernel(const int* __restrict__ eidx, const float* __restrict__ Se,
                    const float* __restrict__ Fe, int* __restrict__ ofs,
                    const int* __restrict__ bsum,
                    int4* __restrict__ recs, int E, int ASZ, int BBINS) {
    int e = blockIdx.x * blockDim.x + threadIdx.x;
    if (e < E) {
        int a, b;
        canon(eidx[e], eidx[E + e], a, b);
        const int key = (a / ASZ) * BBINS + (b >> 3);
        const int pos = atomicAdd(&ofs[key], 1) + bsum[key >> 8];
        _Float16 sh = (_Float16)Se[e];
        _Float16 fh = (_Float16)Fe[e];
        unsigned pk = (unsigned)*(unsigned short*)&sh
                    | ((unsigned)*(unsigned short*)&fh << 16);
        recs[pos] = make_int4(a, b, e, (int)pk);
    }
}

// ---------------- fallback main kernel (R7 core, new A-frag) ----------------

__global__ __launch_bounds__(512, 4)
void edgegate_seg(const _Float16* __restrict__ Hh,
                  const int4*  __restrict__ recs,
                  const int*   __restrict__ vbs,
                  int*         __restrict__ ctr,
                  const float* __restrict__ W1,
                  const float* __restrict__ b1,
                  const float* __restrict__ W2,
                  const float* __restrict__ b2,
                  float*       __restrict__ out)
{
    __shared__ _Float16 w1t[128 * 256];
    __shared__ int tkt[2];
    const int tid = threadIdx.x;
    stage_w1(W1, w1t, tid);

    int xcd;
    asm volatile("s_getreg_b32 %0, hwreg(HW_REG_XCC_ID)" : "=s"(xcd));
    xcd &= (NSEG - 1);

    __syncthreads();

    const int lane = tid & 63;
    const int wave = tid >> 6;
    const int q    = lane >> 4;
    const int cb   = lane & 15;
    const int swz  = cb & 7;
    const float b2v = b2[0];

    int p = 0;
    for (int sidx = 0; sidx < NSEG; ++sidx) {
        const int seg = (xcd + sidx) & (NSEG - 1);
        const int vs  = vbs[seg];
        const int ve  = vbs[seg + 1];
        const int ner = ve - vs;
        if (ner <= 0) continue;
        const int Tt = (ner + 127) >> 7;

        while (true) {
            if (tid == 0) tkt[p] = atomicAdd(&ctr[seg], 1);
            __syncthreads();
            const int t0 = tkt[p];
            p ^= 1;
            if (t0 >= Tt) break;
            const int ebase = vs + (t0 << 7) + (wave << 4);
            edge_tile16(Hh, recs, w1t, W1, b1, W2, b2v, out, ebase, ve, q, cb, swz);
        }
    }
}

// ---------------- ultimate fallback (unsorted) ----------------

__global__ __launch_bounds__(512, 4)
void edgegate_fb(const float* __restrict__ H,
                 const _Float16* __restrict__ Hh,
                 const int*   __restrict__ eidx,
                 const float* __restrict__ Se,
                 const float* __restrict__ Fe,
                 const float* __restrict__ W1,
                 const float* __restrict__ b1,
                 const float* __restrict__ W2,
                 const float* __restrict__ b2,
                 float*       __restrict__ out,
                 int E, int ntiles, int useF16)
{
    __shared__ _Float16 w1t[128 * 256];
    const int tid = threadIdx.x;
    stage_w1(W1, w1t, tid);
    __syncthreads();

    const int lane = tid & 63;
    const int wave = tid >> 6;
    const int q    = lane >> 4;
    const int cb   = lane & 15;
    const int swz  = cb & 7;

    for (int tile = blockIdx.x; tile < ntiles; tile += gridDim.x) {
        const int ebase = tile * 128 + wave * 16;
        int e = ebase + cb;
        if (e >= E) e = E - 1;
        const int u = eidx[e];
        const int v = eidx[E + e];

        f32x4 acc[8];
        #pragma unroll
        for (int t = 0; t < 8; ++t) acc[t] = (f32x4){0.f, 0.f, 0.f, 0.f};

        #pragma unroll
        for (int c8 = 0; c8 < 4; ++c8) {
            half8 ae, ao;
            if (useF16) {
                const _Float16* up = Hh + (size_t)u * 128;
                const _Float16* vp = Hh + (size_t)v * 128;
                const half8 u8 = *(const half8*)(up + (c8 << 5) + (q << 3));
                const half8 v8 = *(const half8*)(vp + (c8 << 5) + (q << 3));
                half8 d8 = u8 - v8;
                ushort8 du = *(ushort8*)&d8;
                du = du & (unsigned short)0x7FFF;
                ae = *(half8*)&du;
                ao = u8 * v8;
            } else {
                const float* up = H + (size_t)u * 128;
                const float* vp = H + (size_t)v * 128;
                #pragma unroll
                for (int j = 0; j < 8; ++j) {
                    const float uu = up[(c8 << 5) + (q << 3) + j];
                    const float vv = vp[(c8 << 5) + (q << 3) + j];
                    ae[j] = (_Float16)fabsf(uu - vv);
                    ao[j] = (_Float16)(uu * vv);
                }
            }
            const int kb0 = ((c8 << 3) + q) ^ swz;
            const int kb1 = ((c8 << 3) + 4 + q) ^ swz;
            #pragma unroll
            for (int t = 0; t < 8; ++t) {
                const half8 b0 = *(const half8*)&w1t[((t << 4) + cb) * 256 + (kb0 << 3)];
                acc[t] = __builtin_amdgcn_mfma_f32_16x16x32_f16(ae, b0, acc[t], 0, 0, 0);
            }
            #pragma unroll
            for (int t = 0; t < 8; ++t) {
                const half8 b1f = *(const half8*)&w1t[((t << 4) + cb) * 256 + (kb1 << 3)];
                acc[t] = __builtin_amdgcn_mfma_f32_16x16x32_f16(ao, b1f, acc[t], 0, 0, 0);
            }
        }

        const int e0  = ebase + (q << 2);
        const int e0c = (e0 + 3 < E) ? e0 : (E - 4);
        const float4 s4 = *(const float4*)(Se + e0c);
        const float4 f4 = *(const float4*)(Fe + e0c);

        float rs0 = 0.f, rs1 = 0.f, rs2 = 0.f, rs3 = 0.f;
        #pragma unroll
        for (int t = 0; t < 8; ++t) {
            const int col    = (t << 4) + cb;
            const float w256 = W1[32768 + col];
            const float w257 = W1[32896 + col];
            const float b1c  = b1[col];
            const float w2c  = W2[col];
            const f32x4 av = acc[t];
            rs0 += silu_f(av[0] + s4.x * w256 + f4.x * w257 + b1c) * w2c;
            rs1 += silu_f(av[1] + s4.y * w256 + f4.y * w257 + b1c) * w2c;
            rs2 += silu_f(av[2] + s4.z * w256 + f4.z * w257 + b1c) * w2c;
            rs3 += silu_f(av[3] + s4.w * w256 + f4.w * w257 + b1c) * w2c;
        }
        #pragma unroll
        for (int off = 1; off < 16; off <<= 1) {
            rs0 += __shfl_xor(rs0, off);
            rs1 += __shfl_xor(rs1, off);
            rs2 += __shfl_xor(rs2, off);
            rs3 += __shfl_xor(rs3, off);
        }
        if (cb == 0 && e0 < E) {
            const float b2v = b2[0];
            out[e0]     = rs0 + b2v;
            out[e0 + 1] = rs1 + b2v;
            out[e0 + 2] = rs2 + b2v;
            out[e0 + 3] = rs3 + b2v;
        }
    }
}

// ---------------- launch ----------------

static inline size_t align256(size_t x) { return (x + 255) & ~(size_t)255; }

extern "C" void kernel_launch(void* const* d_in, const int* in_sizes, int n_in,
                              void* d_out, int out_size, void* d_ws, size_t ws_size,
                              hipStream_t stream)
{
    const float* H    = (const float*)d_in[0];
    const int*   eidx = (const int*)  d_in[1];
    const float* Se   = (const float*)d_in[2];
    const float* Fe   = (const float*)d_in[3];
    const float* W1   = (const float*)d_in[4];
    const float* b1   = (const float*)d_in[5];
    const float* W2   = (const float*)d_in[6];
    const float* b2   = (const float*)d_in[7];
    float* out = (float*)d_out;

    const int nH     = in_sizes[0];            // 6.4M floats
    const int nNodes = nH / 128;               // 50000
    const int E      = in_sizes[2];            // 600000
    const int n4     = nH / 4;
    const int ntiles = (E + 127) / 128;

    const int ASZ   = (nNodes + NSEG - 1) / NSEG;   // 6250
    const int BBINS = (nNodes + 7) >> 3;            // 6250
    const int NB    = NSEG * BBINS;                 // 50000
    const int nb1   = (NB + 255) / 256;             // 196

    const size_t hhB    = (size_t)nH * sizeof(_Float16);
    const size_t off_g  = align256(hhB);                          // hist + ctr
    const size_t off_bs = align256(off_g + (size_t)(NB + 8) * 4); // bsum[512]
    const size_t off_vb = align256(off_bs + 512 * 4);             // vbs[9]
    const size_t off_r  = align256(off_vb + 16 * 4);              // recs
    const size_t need   = off_r + (size_t)E * sizeof(int4);

    if (ws_size >= need && nb1 <= 256) {
        _Float16* Hh   = (_Float16*)((char*)d_ws);
        int*      hist = (int*)     ((char*)d_ws + off_g);
        int*      ctr  = hist + NB;
        int*      bsum = (int*)     ((char*)d_ws + off_bs);
        int*      vbs  = (int*)     ((char*)d_ws + off_vb);
        int4*     recs = (int4*)    ((char*)d_ws + off_r);

        // ---- try the single cooperative mega-kernel first
        int E_ = E, n4_ = n4, NB_ = NB, ASZ_ = ASZ, BBINS_ = BBINS;
        void* args[] = { (void*)&H, (void*)&Hh, (void*)&eidx, (void*)&Se,
                         (void*)&Fe, (void*)&W1, (void*)&b1, (void*)&W2,
                         (void*)&b2, (void*)&out, (void*)&hist, (void*)&bsum,
                         (void*)&vbs, (void*)&recs, (void*)&E_, (void*)&n4_,
                         (void*)&NB_, (void*)&ASZ_, (void*)&BBINS_ };
        hipError_t err = hipLaunchCooperativeKernel(
            (const void*)edgegate_mega, dim3(512), dim3(512), args, 0, stream);

        if (err != hipSuccess) {
            // ---- proven 6-dispatch fallback
            hipLaunchKernelGGL(cvt_zero_kernel, dim3((n4 + 255) / 256), dim3(256),
                               0, stream, H, Hh, n4, hist, NB + 8);
            hipLaunchKernelGGL(hist_kernel, dim3((E + 255) / 256), dim3(256),
                               0, stream, eidx, hist, E, ASZ, BBINS);
            hipLaunchKernelGGL(scan1_kernel, dim3(nb1), dim3(256), 0, stream,
                               hist, bsum, NB);
            hipLaunchKernelGGL(scan2_kernel, dim3(1), dim3(256), 0, stream,
                               bsum, nb1, hist, vbs, BBINS, E);
            hipLaunchKernelGGL(scatter_kernel, dim3((E + 255) / 256), dim3(256),
                               0, stream, eidx, Se, Fe, hist, bsum, recs,
                               E, ASZ, BBINS);
            hipLaunchKernelGGL(edgegate_seg, dim3(512), dim3(512), 0, stream,
                               Hh, recs, vbs, ctr, W1, b1, W2, b2, out);
        }
    } else if (ws_size >= hhB) {
        _Float16* Hh = (_Float16*)d_ws;
        const int grid = (512 < ntiles) ? 512 : ntiles;
        hipLaunchKernelGGL(cvt_zero_kernel, dim3((n4 + 255) / 256), dim3(256),
                           0, stream, H, Hh, n4, (int*)nullptr, 0);
        hipLaunchKernelGGL(edgegate_fb, dim3(grid), dim3(512), 0, stream,
                           H, Hh, eidx, Se, Fe, W1, b1, W2, b2, out, E, ntiles, 1);
    } else {
        const int grid = (512 < ntiles) ? 512 : ntiles;
        hipLaunchKernelGGL(edgegate_fb, dim3(grid), dim3(512), 0, stream,
                           H, (const _Float16*)nullptr, eidx, Se, Fe, W1, b1, W2, b2,
                           out, E, ntiles, 0);
    }
}

// Round 12
// 286.381 us; speedup vs baseline: 2.2497x; 2.2497x over previous
//
#include <hip/hip_runtime.h>

// EdgeGate: out[e] = silu(f(e) @ W1 + b1) @ W2 + b2,
//   f(e) = [|H_u - H_v| (128), H_u*H_v (128), S_e, F_e]   (258)
//
// R12: R11's cooperative mega-kernel regressed hard (557us: union register
// pressure -> 70MB scratch, grid-wide barrier serialization) -> reverted to
// the proven R7 6-dispatch skeleton. ISOLATED change vs R7: K-permutation
// where even chunks = |diff| of 8 consecutive dims and odd chunks = prod of
// the same dims, so A-frags are ae=|u8-v8|, ao=u8*v8 with ZERO element
// interleave VALU (was ~64 ops/tile/lane, ~27% of main VALU).
// Locality machinery proven since R7: canon parity swap, (a/6250, b>>3)
// counting sort, XCC_ID-pinned per-segment ordered ticket queues (1 atomic
// per block per 128-edge tile) + steal. FETCH 53MB, absmax 0.015625.

typedef _Float16       half8   __attribute__((ext_vector_type(8)));
typedef _Float16       half4v  __attribute__((ext_vector_type(4)));
typedef unsigned short ushort8 __attribute__((ext_vector_type(8)));
typedef float          f32x4   __attribute__((ext_vector_type(4)));

#define NSEG    8

__device__ __forceinline__ float silu_f(float x) {
    return x / (1.0f + __expf(-x));
}

__device__ __forceinline__ void canon(int u, int v, int& a, int& b) {
    const int sw = (u ^ v) & 1;       // balanced, symmetric in (u,v)
    a = sw ? v : u;
    b = sw ? u : v;
}

// ---------------- pre-passes (6 dispatches, proven R10 shapes) ----------------

__global__ __launch_bounds__(256)
void cvt_zero_kernel(const float* __restrict__ H, _Float16* __restrict__ Hh,
                     int n4, int* __restrict__ zp, int nz) {
    int i = blockIdx.x * blockDim.x + threadIdx.x;
    if (i < nz) zp[i] = 0;
    if (i < n4) {
        const float4 f = ((const float4*)H)[i];
        half4v h;
        h[0] = (_Float16)f.x; h[1] = (_Float16)f.y;
        h[2] = (_Float16)f.z; h[3] = (_Float16)f.w;
        ((half4v*)Hh)[i] = h;
    }
}

__global__ __launch_bounds__(256)
void hist_kernel(const int* __restrict__ eidx, int* __restrict__ hist,
                 int E, int ASZ, int BBINS) {
    int e = blockIdx.x * blockDim.x + threadIdx.x;
    if (e < E) {
        int a, b;
        canon(eidx[e], eidx[E + e], a, b);
        atomicAdd(&hist[(a / ASZ) * BBINS + (b >> 3)], 1);
    }
}

// intra-block exclusive scan; bsum = block totals
__global__ __launch_bounds__(256)
void scan1_kernel(int* __restrict__ hist, int* __restrict__ bsum, int NB) {
    __shared__ int s[256];
    const int t = threadIdx.x;
    const int i = blockIdx.x * 256 + t;
    const int v = (i < NB) ? hist[i] : 0;
    s[t] = v;
    __syncthreads();
    for (int off = 1; off < 256; off <<= 1) {
        const int x = (t >= off) ? s[t - off] : 0;
        __syncthreads();
        s[t] += x;
        __syncthreads();
    }
    if (i < NB) hist[i] = s[t] - v;
    if (t == 255) bsum[blockIdx.x] = s[255];
}

// exclusive-scan bsum; then segment bounds vbs[0..NSEG]
__global__ __launch_bounds__(256)
void scan2_kernel(int* __restrict__ bsum, int nb1,
                  const int* __restrict__ hist, int* __restrict__ vbs,
                  int BBINS, int E) {
    __shared__ int s[256];
    const int t = threadIdx.x;
    const int v = (t < nb1) ? bsum[t] : 0;
    s[t] = v;
    __syncthreads();
    for (int off = 1; off < 256; off <<= 1) {
        const int x = (t >= off) ? s[t - off] : 0;
        __syncthreads();
        s[t] += x;
        __syncthreads();
    }
    if (t < nb1) bsum[t] = s[t] - v;   // exclusive
    __syncthreads();
    if (t < NSEG) {
        const int idx = t * BBINS;
        vbs[t] = hist[idx] + bsum[idx >> 8];
    } else if (t == NSEG) {
        vbs[NSEG] = E;
    }
}

__global__ __launch_bounds__(256)
void scatter_kernel(const int* __restrict__ eidx, const float* __restrict__ Se,
                    const float* __restrict__ Fe, int* __restrict__ ofs,
                    const int* __restrict__ bsum,
                    int4* __restrict__ recs, int E, int ASZ, int BBINS) {
    int e = blockIdx.x * blockDim.x + threadIdx.x;
    if (e < E) {
        int a, b;
        canon(eidx[e], eidx[E + e], a, b);
        const int key = (a / ASZ) * BBINS + (b >> 3);
        const int pos = atomicAdd(&ofs[key], 1) + bsum[key >> 8];
        _Float16 sh = (_Float16)Se[e];
        _Float16 fh = (_Float16)Fe[e];
        unsigned pk = (unsigned)*(unsigned short*)&sh
                    | ((unsigned)*(unsigned short*)&fh << 16);
        recs[pos] = make_int4(a, b, e, (int)pk);
    }
}

// ---------------- W1 LDS staging (R12 permutation) ----------------
// w1t[n][kp] f16. kp = c*32 + k32 (c = chunk 0..7, k32 = q*8+j).
// src row = (c&1)*128 + (c>>1)*32 + k32  (even c -> |diff| rows, odd -> prod).
// Stored as 16B blocks kb (= kp>>3) at kb ^ (n&7) (XOR swizzle).

__device__ __forceinline__ void stage_w1(const float* __restrict__ W1,
                                         _Float16* __restrict__ w1t, int tid) {
    const int n = tid & 127;
    const int g = tid >> 7;
    #pragma unroll
    for (int i = 0; i < 8; ++i) {
        const int kb = g + (i << 2);
        half8 tmp;
        #pragma unroll
        for (int j = 0; j < 8; ++j) {
            const int kp  = (kb << 3) + j;
            const int c   = kp >> 5;
            const int k32 = kp & 31;
            const int src = ((c & 1) << 7) + ((c >> 1) << 5) + k32;
            tmp[j] = (_Float16)W1[src * 128 + n];
        }
        *(half8*)&w1t[n * 256 + ((kb ^ (n & 7)) << 3)] = tmp;
    }
}

// ---------------- main tile compute (one 16-edge group per wave) ----------------

__device__ __forceinline__ void edge_tile16(
    const _Float16* __restrict__ Hh, const int4* __restrict__ recs,
    const _Float16* __restrict__ w1t,
    const float* __restrict__ W1, const float* __restrict__ b1,
    const float* __restrict__ W2, float b2v, float* __restrict__ out,
    int ebase, int elim, int q, int cb, int swz)
{
    const int e = min(ebase + cb, elim - 1);     // clamp; stores guarded
    const int4 r = recs[e];
    const int a = r.x, b = r.y, oe = r.z;
    const unsigned pk = (unsigned)r.w;
    const unsigned short sl = (unsigned short)(pk & 0xFFFF);
    const unsigned short fl = (unsigned short)(pk >> 16);
    const float Sf = (float)*(const _Float16*)&sl;
    const float Ff = (float)*(const _Float16*)&fl;

    const _Float16* up = Hh + (size_t)a * 128;
    const _Float16* vp = Hh + (size_t)b * 128;

    f32x4 acc[8];
    #pragma unroll
    for (int t = 0; t < 8; ++t) acc[t] = (f32x4){0.f, 0.f, 0.f, 0.f};

    #pragma unroll
    for (int c8 = 0; c8 < 4; ++c8) {
        const half8 u8 = *(const half8*)(up + (c8 << 5) + (q << 3));
        const half8 v8 = *(const half8*)(vp + (c8 << 5) + (q << 3));
        half8 d8 = u8 - v8;
        ushort8 du = *(ushort8*)&d8;
        du = du & (unsigned short)0x7FFF;          // |diff|
        const half8 ae = *(half8*)&du;             // even-chunk A-frag (direct)
        const half8 ao = u8 * v8;                  // odd-chunk  A-frag (direct)

        const int kb0 = ((c8 << 3) + q) ^ swz;        // even chunk 2*c8
        const int kb1 = ((c8 << 3) + 4 + q) ^ swz;    // odd  chunk 2*c8+1
        #pragma unroll
        for (int t = 0; t < 8; ++t) {
            const half8 b0 = *(const half8*)&w1t[((t << 4) + cb) * 256 + (kb0 << 3)];
            acc[t] = __builtin_amdgcn_mfma_f32_16x16x32_f16(ae, b0, acc[t], 0, 0, 0);
        }
        #pragma unroll
        for (int t = 0; t < 8; ++t) {
            const half8 b1f = *(const half8*)&w1t[((t << 4) + cb) * 256 + (kb1 << 3)];
            acc[t] = __builtin_amdgcn_mfma_f32_16x16x32_f16(ao, b1f, acc[t], 0, 0, 0);
        }
    }

    // epilogue: per-quad row data via shuffle from lanes cb = q*4+r
    float s_r[4], f_r[4]; int oe_r[4];
    #pragma unroll
    for (int rr = 0; rr < 4; ++rr) {
        const int src = (q << 2) + rr;
        s_r[rr]  = __shfl(Sf, src);
        f_r[rr]  = __shfl(Ff, src);
        oe_r[rr] = __shfl(oe, src);
    }

    float rs[4] = {0.f, 0.f, 0.f, 0.f};
    #pragma unroll
    for (int t = 0; t < 8; ++t) {
        const int col    = (t << 4) + cb;
        const float w256 = W1[32768 + col];
        const float w257 = W1[32896 + col];
        const float b1c  = b1[col];
        const float w2c  = W2[col];
        const f32x4 av = acc[t];
        #pragma unroll
        for (int rr = 0; rr < 4; ++rr)
            rs[rr] += silu_f(av[rr] + s_r[rr] * w256 + f_r[rr] * w257 + b1c) * w2c;
    }

    #pragma unroll
    for (int off = 1; off < 16; off <<= 1) {
        #pragma unroll
        for (int rr = 0; rr < 4; ++rr) rs[rr] += __shfl_xor(rs[rr], off);
    }

    if (cb == 0) {
        #pragma unroll
        for (int rr = 0; rr < 4; ++rr) {
            const int pe = ebase + (q << 2) + rr;
            if (pe < elim) out[oe_r[rr]] = rs[rr] + b2v;
        }
    }
}

// ---------------- main kernel (R7 skeleton) ----------------

__global__ __launch_bounds__(512, 4)
void edgegate_seg(const _Float16* __restrict__ Hh,
                  const int4*  __restrict__ recs,
                  const int*   __restrict__ vbs,   // [9] segment edge bounds
                  int*         __restrict__ ctr,   // [8] per-segment ticket ctrs
                  const float* __restrict__ W1,
                  const float* __restrict__ b1,
                  const float* __restrict__ W2,
                  const float* __restrict__ b2,
                  float*       __restrict__ out)
{
    __shared__ _Float16 w1t[128 * 256];   // 64 KiB
    __shared__ int tkt[2];                // parity ticket slots
    const int tid = threadIdx.x;
    stage_w1(W1, w1t, tid);

    int xcd;
    asm volatile("s_getreg_b32 %0, hwreg(HW_REG_XCC_ID)" : "=s"(xcd));
    xcd &= (NSEG - 1);

    __syncthreads();   // w1t ready

    const int lane = tid & 63;
    const int wave = tid >> 6;
    const int q    = lane >> 4;
    const int cb   = lane & 15;
    const int swz  = cb & 7;
    const float b2v = b2[0];

    int p = 0;
    // own segment first, then steal (correct under any dispatch mapping)
    for (int sidx = 0; sidx < NSEG; ++sidx) {
        const int seg = (xcd + sidx) & (NSEG - 1);
        const int vs  = vbs[seg];
        const int ve  = vbs[seg + 1];
        const int ner = ve - vs;
        if (ner <= 0) continue;
        const int Tt = (ner + 127) >> 7;    // 128-edge tickets

        while (true) {
            if (tid == 0) tkt[p] = atomicAdd(&ctr[seg], 1);
            __syncthreads();
            const int t0 = tkt[p];
            p ^= 1;
            if (t0 >= Tt) break;
            const int ebase = vs + (t0 << 7) + (wave << 4);
            edge_tile16(Hh, recs, w1t, W1, b1, W2, b2v, out, ebase, ve, q, cb, swz);
        }
    }
}

// ---------------- fallback (unsorted) ----------------

__global__ __launch_bounds__(512, 4)
void edgegate_fb(const float* __restrict__ H,
                 const _Float16* __restrict__ Hh,
                 const int*   __restrict__ eidx,
                 const float* __restrict__ Se,
                 const float* __restrict__ Fe,
                 const float* __restrict__ W1,
                 const float* __restrict__ b1,
                 const float* __restrict__ W2,
                 const float* __restrict__ b2,
                 float*       __restrict__ out,
                 int E, int ntiles, int useF16)
{
    __shared__ _Float16 w1t[128 * 256];
    const int tid = threadIdx.x;
    stage_w1(W1, w1t, tid);
    __syncthreads();

    const int lane = tid & 63;
    const int wave = tid >> 6;
    const int q    = lane >> 4;
    const int cb   = lane & 15;
    const int swz  = cb & 7;

    for (int tile = blockIdx.x; tile < ntiles; tile += gridDim.x) {
        const int ebase = tile * 128 + wave * 16;
        int e = ebase + cb;
        if (e >= E) e = E - 1;
        const int u = eidx[e];
        const int v = eidx[E + e];

        f32x4 acc[8];
        #pragma unroll
        for (int t = 0; t < 8; ++t) acc[t] = (f32x4){0.f, 0.f, 0.f, 0.f};

        #pragma unroll
        for (int c8 = 0; c8 < 4; ++c8) {
            half8 ae, ao;
            if (useF16) {
                const _Float16* up = Hh + (size_t)u * 128;
                const _Float16* vp = Hh + (size_t)v * 128;
                const half8 u8 = *(const half8*)(up + (c8 << 5) + (q << 3));
                const half8 v8 = *(const half8*)(vp + (c8 << 5) + (q << 3));
                half8 d8 = u8 - v8;
                ushort8 du = *(ushort8*)&d8;
                du = du & (unsigned short)0x7FFF;
                ae = *(half8*)&du;
                ao = u8 * v8;
            } else {
                const float* up = H + (size_t)u * 128;
                const float* vp = H + (size_t)v * 128;
                #pragma unroll
                for (int j = 0; j < 8; ++j) {
                    const float uu = up[(c8 << 5) + (q << 3) + j];
                    const float vv = vp[(c8 << 5) + (q << 3) + j];
                    ae[j] = (_Float16)fabsf(uu - vv);
                    ao[j] = (_Float16)(uu * vv);
                }
            }
            const int kb0 = ((c8 << 3) + q) ^ swz;
            const int kb1 = ((c8 << 3) + 4 + q) ^ swz;
            #pragma unroll
            for (int t = 0; t < 8; ++t) {
                const half8 b0 = *(const half8*)&w1t[((t << 4) + cb) * 256 + (kb0 << 3)];
                acc[t] = __builtin_amdgcn_mfma_f32_16x16x32_f16(ae, b0, acc[t], 0, 0, 0);
            }
            #pragma unroll
            for (int t = 0; t < 8; ++t) {
                const half8 b1f = *(const half8*)&w1t[((t << 4) + cb) * 256 + (kb1 << 3)];
                acc[t] = __builtin_amdgcn_mfma_f32_16x16x32_f16(ao, b1f, acc[t], 0, 0, 0);
            }
        }

        const int e0  = ebase + (q << 2);
        const int e0c = (e0 + 3 < E) ? e0 : (E - 4);
        const float4 s4 = *(const float4*)(Se + e0c);
        const float4 f4 = *(const float4*)(Fe + e0c);

        float rs0 = 0.f, rs1 = 0.f, rs2 = 0.f, rs3 = 0.f;
        #pragma unroll
        for (int t = 0; t < 8; ++t) {
            const int col    = (t << 4) + cb;
            const float w256 = W1[32768 + col];
            const float w257 = W1[32896 + col];
            const float b1c  = b1[col];
            const float w2c  = W2[col];
            const f32x4 av = acc[t];
            rs0 += silu_f(av[0] + s4.x * w256 + f4.x * w257 + b1c) * w2c;
            rs1 += silu_f(av[1] + s4.y * w256 + f4.y * w257 + b1c) * w2c;
            rs2 += silu_f(av[2] + s4.z * w256 + f4.z * w257 + b1c) * w2c;
            rs3 += silu_f(av[3] + s4.w * w256 + f4.w * w257 + b1c) * w2c;
        }
        #pragma unroll
        for (int off = 1; off < 16; off <<= 1) {
            rs0 += __shfl_xor(rs0, off);
            rs1 += __shfl_xor(rs1, off);
            rs2 += __shfl_xor(rs2, off);
            rs3 += __shfl_xor(rs3, off);
        }
        if (cb == 0 && e0 < E) {
            const float b2v = b2[0];
            out[e0]     = rs0 + b2v;
            out[e0 + 1] = rs1 + b2v;
            out[e0 + 2] = rs2 + b2v;
            out[e0 + 3] = rs3 + b2v;
        }
    }
}

// ---------------- launch ----------------

static inline size_t align256(size_t x) { return (x + 255) & ~(size_t)255; }

extern "C" void kernel_launch(void* const* d_in, const int* in_sizes, int n_in,
                              void* d_out, int out_size, void* d_ws, size_t ws_size,
                              hipStream_t stream)
{
    const float* H    = (const float*)d_in[0];
    const int*   eidx = (const int*)  d_in[1];
    const float* Se   = (const float*)d_in[2];
    const float* Fe   = (const float*)d_in[3];
    const float* W1   = (const float*)d_in[4];
    const float* b1   = (const float*)d_in[5];
    const float* W2   = (const float*)d_in[6];
    const float* b2   = (const float*)d_in[7];
    float* out = (float*)d_out;

    const int nH     = in_sizes[0];            // 6.4M floats
    const int nNodes = nH / 128;               // 50000
    const int E      = in_sizes[2];            // 600000
    const int n4     = nH / 4;
    const int ntiles = (E + 127) / 128;

    const int ASZ   = (nNodes + NSEG - 1) / NSEG;   // 6250
    const int BBINS = (nNodes + 7) >> 3;            // 6250
    const int NB    = NSEG * BBINS;                 // 50000
    const int nb1   = (NB + 255) / 256;             // 196

    const size_t hhB    = (size_t)nH * sizeof(_Float16);
    const size_t off_g  = align256(hhB);                          // hist + ctr
    const size_t off_bs = align256(off_g + (size_t)(NB + 8) * 4); // bsum
    const size_t off_vb = align256(off_bs + 256 * 4);             // vbs[9]
    const size_t off_r  = align256(off_vb + 16 * 4);              // recs
    const size_t need   = off_r + (size_t)E * sizeof(int4);

    if (ws_size >= need && nb1 <= 256) {
        _Float16* Hh   = (_Float16*)((char*)d_ws);
        int*      hist = (int*)     ((char*)d_ws + off_g);
        int*      ctr  = hist + NB;                       // 8 counters
        int*      bsum = (int*)     ((char*)d_ws + off_bs);
        int*      vbs  = (int*)     ((char*)d_ws + off_vb);
        int4*     recs = (int4*)    ((char*)d_ws + off_r);

        hipLaunchKernelGGL(cvt_zero_kernel, dim3((n4 + 255) / 256), dim3(256),
                           0, stream, H, Hh, n4, hist, NB + 8);
        hipLaunchKernelGGL(hist_kernel, dim3((E + 255) / 256), dim3(256),
                           0, stream, eidx, hist, E, ASZ, BBINS);
        hipLaunchKernelGGL(scan1_kernel, dim3(nb1), dim3(256), 0, stream,
                           hist, bsum, NB);
        hipLaunchKernelGGL(scan2_kernel, dim3(1), dim3(256), 0, stream,
                           bsum, nb1, hist, vbs, BBINS, E);
        hipLaunchKernelGGL(scatter_kernel, dim3((E + 255) / 256), dim3(256),
                           0, stream, eidx, Se, Fe, hist, bsum, recs,
                           E, ASZ, BBINS);
        hipLaunchKernelGGL(edgegate_seg, dim3(512), dim3(512), 0, stream,
                           Hh, recs, vbs, ctr, W1, b1, W2, b2, out);
    } else if (ws_size >= hhB) {
        _Float16* Hh = (_Float16*)d_ws;
        const int grid = (512 < ntiles) ? 512 : ntiles;
        hipLaunchKernelGGL(cvt_zero_kernel, dim3((n4 + 255) / 256), dim3(256),
                           0, stream, H, Hh, n4, (int*)nullptr, 0);
        hipLaunchKernelGGL(edgegate_fb, dim3(grid), dim3(512), 0, stream,
                           H, Hh, eidx, Se, Fe, W1, b1, W2, b2, out, E, ntiles, 1);
    } else {
        const int grid = (512 < ntiles) ? 512 : ntiles;
        hipLaunchKernelGGL(edgegate_fb, dim3(grid), dim3(512), 0, stream,
                           H, (const _Float16*)nullptr, eidx, Se, Fe, W1, b1, W2, b2,
                           out, E, ntiles, 0);
    }
}